// Round 4
// baseline (48030.347 us; speedup 1.0000x reference)
//
#include <hip/hip_runtime.h>
#include <hip/hip_bf16.h>
#include <stdint.h>

typedef __attribute__((ext_vector_type(8))) short short8;
typedef __attribute__((ext_vector_type(4))) short short4v;
typedef __attribute__((ext_vector_type(4))) float f32x4;
typedef _Float16 half2v __attribute__((ext_vector_type(2)));
typedef _Float16 half8 __attribute__((ext_vector_type(8)));
using bf16 = __hip_bfloat16;

__device__ __forceinline__ float bfb2f(unsigned short u) {
  union { unsigned u; float f; } x; x.u = ((unsigned)u) << 16; return x.f;
}
__device__ __forceinline__ unsigned short f2bfb(float f) {
  union { float f; unsigned u; } x; x.f = f;
  unsigned r = x.u + 0x7FFFu + ((x.u >> 16) & 1u);
  return (unsigned short)(r >> 16);
}
__device__ __forceinline__ float sigf(float x) { return 1.0f / (1.0f + __expf(-x)); }
__device__ __forceinline__ float tanhf_(float x) {
  x = fminf(fmaxf(x, -15.f), 15.f);
  float e = __expf(2.f * x);
  return 1.f - 2.f / (e + 1.f);
}
__device__ __forceinline__ f32x4 mfma16(short8 a, short8 b, f32x4 c) {
  return __builtin_amdgcn_mfma_f32_16x16x32_bf16(a, b, c, 0, 0, 0);
}
__device__ __forceinline__ int swz(int b) { return b ^ (((b >> 6) & 7) << 4); }

// f16 dot-8 with fp32 accumulate (v_dot2_f32_f16 when available)
__device__ __forceinline__ float dot8(half8 w, half8 x, float acc) {
#if __has_builtin(__builtin_amdgcn_fdot2)
  half2v w0 = {w[0], w[1]}, w1 = {w[2], w[3]}, w2 = {w[4], w[5]}, w3 = {w[6], w[7]};
  half2v x0 = {x[0], x[1]}, x1 = {x[2], x[3]}, x2 = {x[4], x[5]}, x3 = {x[6], x[7]};
  acc = __builtin_amdgcn_fdot2(w0, x0, acc, false);
  acc = __builtin_amdgcn_fdot2(w1, x1, acc, false);
  acc = __builtin_amdgcn_fdot2(w2, x2, acc, false);
  acc = __builtin_amdgcn_fdot2(w3, x3, acc, false);
#else
#pragma unroll
  for (int i = 0; i < 8; ++i) acc += (float)w[i] * (float)x[i];
#endif
  return acc;
}

// ---------------- prep / packing kernels ----------------

__global__ void k_pack_apack(const float* __restrict__ w, bf16* __restrict__ out, int CO, int CI) {
  int idx = blockIdx.x * 256 + threadIdx.x;
  int total = 9 * CO * CI;
  if (idx >= total) return;
  int ci = idx % CI; int r = idx / CI; int co = r % CO; int s = r / CO;
  ((unsigned short*)out)[(s * CO + co) * CI + ci] = f2bfb(w[(co * CI + ci) * 9 + s]);
}

__global__ void k_castT512(const float* __restrict__ src, bf16* __restrict__ dst) {
  int idx = blockIdx.x * 256 + threadIdx.x;
  if (idx >= 262144) return;
  int k = idx >> 9, nn = idx & 511;
  ((unsigned short*)dst)[nn * 512 + k] = f2bfb(src[idx]);
}

__global__ void k_castf16(const float* __restrict__ src, _Float16* __restrict__ dst, int n) {
  int idx = blockIdx.x * 256 + threadIdx.x;
  if (idx < n) dst[idx] = (_Float16)src[idx];
}

// gates weights f16 row-major [j][1120]: k<80 emb | 16 zero | O(512) | h(512)
__global__ void k_wgf(const float* __restrict__ Wx, const float* __restrict__ Wh, _Float16* __restrict__ out) {
  int idx = blockIdx.x * 256 + threadIdx.x;
  if (idx >= 2293760) return;
  int k = idx % 1120, j = idx / 1120;
  float v = 0.f;
  if (k < 80) v = Wx[j * 592 + k];
  else if (k < 96) v = 0.f;
  else if (k < 608) v = Wx[j * 592 + (k - 16)];
  else v = Wh[j * 512 + (k - 608)];
  out[idx] = (_Float16)v;
}
// Wh_att transposed f16: WhaF[n][k] = Wha[k][n]
__global__ void k_whaf(const float* __restrict__ Wha, _Float16* __restrict__ out) {
  int idx = blockIdx.x * 256 + threadIdx.x;
  if (idx >= 262144) return;
  int k = idx & 511, n = idx >> 9;
  out[idx] = (_Float16)Wha[k * 512 + n];
}
// W_out f16 [512][512], rows >=500 zero
__global__ void k_woutf(const float* __restrict__ W, _Float16* __restrict__ out) {
  int idx = blockIdx.x * 256 + threadIdx.x;
  if (idx >= 262144) return;
  int v = idx >> 9;
  out[idx] = (v < 500) ? (_Float16)W[idx] : (_Float16)0.f;
}

// ---------------- CNN ----------------

__global__ __launch_bounds__(256) void k_conv1(const float* __restrict__ Xin, const float* __restrict__ w1,
                                               const float* __restrict__ b1, bf16* __restrict__ out) {
  __shared__ float wsm[576];
  __shared__ float xt[4][10];
  const int tid = threadIdx.x;
  const int n = blockIdx.z, y2 = blockIdx.y, xb = blockIdx.x * 4;
  for (int i = tid; i < 576; i += 256) wsm[i] = w1[i];
  if (tid < 40) {
    int rr = tid / 10, cc = tid % 10;
    int gy = 2 * y2 - 1 + rr, gx = 2 * xb - 1 + cc;
    float v = 0.f;
    if (gy >= 0 && gy < 64 && gx >= 0 && gx < 512) v = Xin[n * 32768 + gy * 512 + gx];
    xt[rr][cc] = v;
  }
  __syncthreads();
  const int co = tid & 63, xl = tid >> 6;
  const float bb = b1[co];
  float mx = 0.f;
#pragma unroll
  for (int py = 0; py < 2; ++py)
#pragma unroll
    for (int px = 0; px < 2; ++px) {
      float s = bb;
#pragma unroll
      for (int dy = 0; dy < 3; ++dy)
#pragma unroll
        for (int dx = 0; dx < 3; ++dx)
          s = fmaf(wsm[co * 9 + dy * 3 + dx], xt[py + dy][2 * xl + px + dx], s);
      mx = fmaxf(mx, fmaxf(s, 0.f));
    }
  ((unsigned short*)out)[((n * 34 + y2 + 1) * 258 + (xb + xl) + 1) * 64 + co] = f2bfb(mx);
}

template <int CI, int CO, int H, int W, int MODE>
__global__ __launch_bounds__(256) void k_convgemm(const bf16* __restrict__ inP, const bf16* __restrict__ apack,
                                                  const float* __restrict__ bias, bf16* __restrict__ outp) {
  constexpr int Hp = H + 2, Wp = W + 2;
  __shared__ __align__(16) char As[8192];
  __shared__ __align__(16) char Bs[8192];
  const int tid = threadIdx.x, lane = tid & 63, wv = tid >> 6;
  const int lm = lane & 15, kh = lane >> 4;
  const int wm = wv & 1, wn = wv >> 1;
  const int p0 = blockIdx.x * 128, m0 = blockIdx.y * 128;
  const int n = p0 / (H * W), rem = p0 % (H * W);
  const int y = rem / W, x0 = rem % W;
  const long long pixbase = ((long long)(n * Hp + y) * Wp + x0) * CI;
  f32x4 acc[4][4];
#pragma unroll
  for (int i = 0; i < 4; ++i)
#pragma unroll
    for (int j = 0; j < 4; ++j) acc[i][j] = (f32x4){0.f, 0.f, 0.f, 0.f};
  const int r = tid >> 1, e0 = (tid & 1) * 16;
  const int wb = r * 64 + e0 * 2;
  for (int s = 0; s < 9; ++s) {
    const int dy = s / 3, dx = s % 3;
    const bf16* bsrc = inP + pixbase + (dy * Wp + dx) * CI;
    const bf16* asrc = apack + (s * CO + m0) * CI;
    for (int cc = 0; cc < CI / 32; ++cc) {
      short8 av0 = *(const short8*)(asrc + r * CI + cc * 32 + e0);
      short8 av1 = *(const short8*)(asrc + r * CI + cc * 32 + e0 + 8);
      short8 bv0 = *(const short8*)(bsrc + (long long)r * CI + cc * 32 + e0);
      short8 bv1 = *(const short8*)(bsrc + (long long)r * CI + cc * 32 + e0 + 8);
      __syncthreads();
      *(short8*)(void*)(As + swz(wb)) = av0;
      *(short8*)(void*)(As + swz(wb + 16)) = av1;
      *(short8*)(void*)(Bs + swz(wb)) = bv0;
      *(short8*)(void*)(Bs + swz(wb + 16)) = bv1;
      __syncthreads();
      short8 af[4], bg[4];
#pragma unroll
      for (int i = 0; i < 4; ++i)
        af[i] = *(const short8*)(const void*)(As + swz((wm * 64 + i * 16 + lm) * 64 + kh * 16));
#pragma unroll
      for (int j = 0; j < 4; ++j)
        bg[j] = *(const short8*)(const void*)(Bs + swz((wn * 64 + j * 16 + lm) * 64 + kh * 16));
#pragma unroll
      for (int i = 0; i < 4; ++i)
#pragma unroll
        for (int j = 0; j < 4; ++j) acc[i][j] = mfma16(af[i], bg[j], acc[i][j]);
    }
  }
#pragma unroll
  for (int i = 0; i < 4; ++i) {
    const int co = m0 + wm * 64 + i * 16 + kh * 4;
    float b4[4];
#pragma unroll
    for (int rr = 0; rr < 4; ++rr) b4[rr] = bias[co + rr];
#pragma unroll
    for (int j = 0; j < 4; ++j) {
      const int pix = p0 + wn * 64 + j * 16 + lm;
      short4v pk;
#pragma unroll
      for (int rr = 0; rr < 4; ++rr) {
        float v = fmaxf(acc[i][j][rr] + b4[rr], 0.f);
        pk[rr] = (short)f2bfb(v);
      }
      if constexpr (MODE == 0) {
        *(short4v*)(void*)(outp + (long long)pix * CO + co) = pk;
      } else {
        const int nn = pix / (H * W), r2 = pix % (H * W);
        const int yy = r2 / W, xx = r2 % W;
        *(short4v*)(void*)(outp + ((long long)(nn * Hp + yy + 1) * Wp + xx + 1) * CO + co) = pk;
      }
    }
  }
}

__global__ void k_pool(const bf16* __restrict__ src, bf16* __restrict__ dst,
                       int H, int W, int C, int OHP, int OWP, int pad) {
  const int idx = blockIdx.x * 256 + threadIdx.x;
  const int C8 = C >> 3;
  const int c8 = idx % C8; int tmp = idx / C8;
  const int x2 = tmp % (W >> 1); tmp /= (W >> 1);
  const int y2 = tmp % (H >> 1); const int n = tmp / (H >> 1);
  if (n >= 32) return;
  const long long sbase = ((long long)(n * H + 2 * y2) * W + 2 * x2) * C + c8 * 8;
  short8 a = *(const short8*)(src + sbase);
  short8 b = *(const short8*)(src + sbase + C);
  short8 c = *(const short8*)(src + sbase + (long long)W * C);
  short8 d = *(const short8*)(src + sbase + (long long)W * C + C);
  short8 o;
#pragma unroll
  for (int e = 0; e < 8; ++e) {
    float m = fmaxf(fmaxf(bfb2f((unsigned short)a[e]), bfb2f((unsigned short)b[e])),
                    fmaxf(bfb2f((unsigned short)c[e]), bfb2f((unsigned short)d[e])));
    o[e] = (short)f2bfb(m);
  }
  *(short8*)(void*)(dst + ((long long)(n * OHP + y2 + pad) * OWP + x2 + pad) * C + c8 * 8) = o;
}

// tiled transpose: VF[(b*512+c)*512+l] = f16(Vbuf[(b*512+l)*512+c])
__global__ __launch_bounds__(256) void k_vtrans(const bf16* __restrict__ V, _Float16* __restrict__ VF) {
  __shared__ _Float16 tile[64][65];
  const int b = blockIdx.z, lt = blockIdx.y * 64, ct = blockIdx.x * 64;
  const int tid = threadIdx.x;
  const int row = tid >> 2, cg = (tid & 3) * 16;
  const unsigned short* src = (const unsigned short*)V + ((size_t)(b * 512 + lt + row) * 512) + ct + cg;
#pragma unroll
  for (int i = 0; i < 16; ++i) tile[row][cg + i] = (_Float16)bfb2f(src[i]);
  __syncthreads();
  const int crow = tid >> 2, lg = (tid & 3) * 16;
  _Float16* dst = VF + ((size_t)(b * 512 + ct + crow) * 512) + lt + lg;
#pragma unroll
  for (int i = 0; i < 16; ++i) dst[i] = tile[lg + i][crow];
}

// Vproj GEMM: M=16384 (b,l), N=512, K=512; writes e2v = exp(2*(V@Wv + b_att)) as f32
__global__ __launch_bounds__(256) void k_gemm_vproj(const bf16* __restrict__ Vb, const bf16* __restrict__ WvT,
                                                    const float* __restrict__ batt, float* __restrict__ E2V) {
  __shared__ __align__(16) char As[8192];
  __shared__ __align__(16) char Bs[8192];
  const int tid = threadIdx.x, lane = tid & 63, wv = tid >> 6;
  const int lm = lane & 15, kh = lane >> 4;
  const int wm = wv & 1, wn = wv >> 1;
  const int n0 = blockIdx.x * 128, m0 = blockIdx.y * 128;
  f32x4 acc[4][4];
#pragma unroll
  for (int i = 0; i < 4; ++i)
#pragma unroll
    for (int j = 0; j < 4; ++j) acc[i][j] = (f32x4){0.f, 0.f, 0.f, 0.f};
  const int r = tid >> 1, e0 = (tid & 1) * 16;
  const int wb = r * 64 + e0 * 2;
  for (int cc = 0; cc < 16; ++cc) {
    short8 av0 = *(const short8*)(Vb + (m0 + r) * 512 + cc * 32 + e0);
    short8 av1 = *(const short8*)(Vb + (m0 + r) * 512 + cc * 32 + e0 + 8);
    short8 bv0 = *(const short8*)(WvT + (n0 + r) * 512 + cc * 32 + e0);
    short8 bv1 = *(const short8*)(WvT + (n0 + r) * 512 + cc * 32 + e0 + 8);
    __syncthreads();
    *(short8*)(void*)(As + swz(wb)) = av0;
    *(short8*)(void*)(As + swz(wb + 16)) = av1;
    *(short8*)(void*)(Bs + swz(wb)) = bv0;
    *(short8*)(void*)(Bs + swz(wb + 16)) = bv1;
    __syncthreads();
    short8 af[4], bg[4];
#pragma unroll
    for (int i = 0; i < 4; ++i)
      af[i] = *(const short8*)(const void*)(As + swz((wm * 64 + i * 16 + lm) * 64 + kh * 16));
#pragma unroll
    for (int j = 0; j < 4; ++j)
      bg[j] = *(const short8*)(const void*)(Bs + swz((wn * 64 + j * 16 + lm) * 64 + kh * 16));
#pragma unroll
    for (int i = 0; i < 4; ++i)
#pragma unroll
      for (int j = 0; j < 4; ++j) acc[i][j] = mfma16(af[i], bg[j], acc[i][j]);
  }
#pragma unroll
  for (int i = 0; i < 4; ++i)
#pragma unroll
    for (int j = 0; j < 4; ++j) {
      const int nn = n0 + wn * 64 + j * 16 + lm;
      const float ba = batt[nn];
#pragma unroll
      for (int rr = 0; rr < 4; ++rr) {
        const int m = m0 + wm * 64 + i * 16 + kh * 4 + rr;
        E2V[(size_t)m * 512 + nn] = __expf(2.f * (acc[i][j][rr] + ba));
      }
    }
}

// ---------------- decoder: 1 block per batch element, zero cross-block sync ----------------
// tanh(Vproj+hW) = 1 - 2/(1 + e2v*e2hw); all weights f16, fp32 accumulate.
__global__ __launch_bounds__(1024) void k_dec(
    const _Float16* __restrict__ WgF, const _Float16* __restrict__ WhaF,
    const _Float16* __restrict__ WOF, const _Float16* __restrict__ WoutF,
    const float* __restrict__ e2v, const _Float16* __restrict__ VF,
    const _Float16* __restrict__ Ef, const int* __restrict__ labels,
    const float* __restrict__ bl, const float* __restrict__ beta,
    float* __restrict__ out) {
  const int tid = threadIdx.x, b = blockIdx.x;
  __shared__ _Float16 xk[1120];   // gates input: [emb80|z16|O512|h512]
  __shared__ float cst[512];      // LSTM cell state
  __shared__ _Float16 hc16[1024]; // [h | ctx]
  __shared__ float gl[2048];      // gates out / phase scratch
  __shared__ float hb[1024];      // interleaved (e^{2hW[n]}, beta[n])
  __shared__ float sbuf[512];
  __shared__ float alf[512];      // unnormalized softmax weights
  __shared__ float blL[2048];
  __shared__ float betaL[512];
  __shared__ float wred[17];

  for (int i = tid; i < 1120; i += 1024) xk[i] = (_Float16)0.f;
  if (tid < 512) cst[tid] = 0.f;
  for (int i = tid; i < 2048; i += 1024) blL[i] = bl[i];
  if (tid < 512) betaL[tid] = beta[tid];
  __syncthreads();

  for (int t = 0; t < 150; ++t) {
    // stage embedding for this step
    if (tid < 80) {
      const int id = (t == 0) ? 497 : labels[b * 150 + (t - 1)];
      xk[tid] = Ef[id * 80 + tid];
    }
    __syncthreads();
    // gates GEMV: 2048 outputs, K=1120; rows tid and tid+1024
    {
      float a0 = 0.f, a1 = 0.f;
      const half8* w0 = (const half8*)(WgF + (size_t)tid * 1120);
      const half8* w1 = (const half8*)(WgF + (size_t)(tid + 1024) * 1120);
      const half8* xp = (const half8*)xk;
      for (int i = 0; i < 140; ++i) {
        half8 xv = xp[i];
        a0 = dot8(w0[i], xv, a0);
        a1 = dot8(w1[i], xv, a1);
      }
      gl[tid] = a0;
      gl[tid + 1024] = a1;
    }
    __syncthreads();
    // LSTM pointwise
    if (tid < 512) {
      float ig = gl[tid] + blL[tid];
      float fg = gl[512 + tid] + blL[512 + tid];
      float gg = gl[1024 + tid] + blL[1024 + tid];
      float og = gl[1536 + tid] + blL[1536 + tid];
      float c = sigf(fg) * cst[tid] + sigf(ig) * tanhf_(gg);
      cst[tid] = c;
      _Float16 h16 = (_Float16)(sigf(og) * tanhf_(c));
      hc16[tid] = h16;
      xk[608 + tid] = h16;  // h for next step's gates
    }
    __syncthreads();
    // hW = h @ Wh_att  (K split in 2), then e^{2hW} paired with beta
    {
      const int n = tid & 511, hf = tid >> 9;
      float a = 0.f;
      const half8* w = (const half8*)(WhaF + (size_t)n * 512 + hf * 256);
      const half8* hp = (const half8*)(hc16 + hf * 256);
      for (int i = 0; i < 32; ++i) a = dot8(w[i], hp[i], a);
      gl[hf * 512 + n] = a;
    }
    __syncthreads();
    if (tid < 512) {
      float hw = gl[tid] + gl[512 + tid];
      hb[2 * tid] = __expf(2.f * hw);
      hb[2 * tid + 1] = betaL[tid];
    }
    __syncthreads();
    // scores[l] = sum_n beta_n * (1 - 2/(1 + e2v*e2hw))  (n split in 2)
    {
      const int l = tid & 511, hf = tid >> 9;
      const f32x4* ep = (const f32x4*)(e2v + ((size_t)(b * 512 + l)) * 512 + hf * 256);
      const f32x4* hbp = (const f32x4*)(hb + hf * 512);
      float acc = 0.f;
      for (int i = 0; i < 64; ++i) {
        f32x4 z4v = ep[i];
        f32x4 p0 = hbp[2 * i], p1 = hbp[2 * i + 1];
        float r0 = __builtin_amdgcn_rcpf(1.f + z4v[0] * p0[0]);
        acc = fmaf(p0[1], fmaf(-2.f, r0, 1.f), acc);
        float r1 = __builtin_amdgcn_rcpf(1.f + z4v[1] * p0[2]);
        acc = fmaf(p0[3], fmaf(-2.f, r1, 1.f), acc);
        float r2 = __builtin_amdgcn_rcpf(1.f + z4v[2] * p1[0]);
        acc = fmaf(p1[1], fmaf(-2.f, r2, 1.f), acc);
        float r3 = __builtin_amdgcn_rcpf(1.f + z4v[3] * p1[2]);
        acc = fmaf(p1[3], fmaf(-2.f, r3, 1.f), acc);
      }
      gl[hf * 512 + l] = acc;
    }
    __syncthreads();
    // softmax over 512 l
    if (tid < 512) {
      float s = gl[tid] + gl[512 + tid];
      sbuf[tid] = s;
      float m = s;
#pragma unroll
      for (int off = 32; off >= 1; off >>= 1) m = fmaxf(m, __shfl_xor(m, off, 64));
      if ((tid & 63) == 0) wred[tid >> 6] = m;
    }
    __syncthreads();
    if (tid < 512) {
      float m = fmaxf(fmaxf(fmaxf(wred[0], wred[1]), fmaxf(wred[2], wred[3])),
                      fmaxf(fmaxf(wred[4], wred[5]), fmaxf(wred[6], wred[7])));
      float e = __expf(sbuf[tid] - m);
      alf[tid] = e;
      float sm = e;
#pragma unroll
      for (int off = 32; off >= 1; off >>= 1) sm += __shfl_xor(sm, off, 64);
      if ((tid & 63) == 0) wred[8 + (tid >> 6)] = sm;
    }
    __syncthreads();
    // ctx[c] = (1/Z) * sum_l a_l * V[l][c]   (l split in 2)
    {
      const int c = tid & 511, lh = tid >> 9;
      const half8* vp = (const half8*)(VF + ((size_t)(b * 512 + c)) * 512 + lh * 256);
      const f32x4* ap = (const f32x4*)(alf + lh * 256);
      float acc = 0.f;
      for (int i = 0; i < 32; ++i) {
        half8 v8 = vp[i];
        f32x4 a0 = ap[2 * i], a1 = ap[2 * i + 1];
        acc = fmaf(a0[0], (float)v8[0], acc);
        acc = fmaf(a0[1], (float)v8[1], acc);
        acc = fmaf(a0[2], (float)v8[2], acc);
        acc = fmaf(a0[3], (float)v8[3], acc);
        acc = fmaf(a1[0], (float)v8[4], acc);
        acc = fmaf(a1[1], (float)v8[5], acc);
        acc = fmaf(a1[2], (float)v8[6], acc);
        acc = fmaf(a1[3], (float)v8[7], acc);
      }
      gl[lh * 512 + c] = acc;
    }
    __syncthreads();
    if (tid < 512) {
      float rz = 1.f / (wred[8] + wred[9] + wred[10] + wred[11] +
                        wred[12] + wred[13] + wred[14] + wred[15]);
      hc16[512 + tid] = (_Float16)((gl[tid] + gl[512 + tid]) * rz);
    }
    __syncthreads();
    // O = tanh([h|ctx] @ W_O^T)   (K=1024 split in 2)
    {
      const int o = tid & 511, kh2 = tid >> 9;
      const half8* w = (const half8*)(WOF + (size_t)o * 1024 + kh2 * 512);
      const half8* hp = (const half8*)(hc16 + kh2 * 512);
      float acc = 0.f;
      for (int i = 0; i < 64; ++i) acc = dot8(w[i], hp[i], acc);
      gl[kh2 * 512 + o] = acc;
    }
    __syncthreads();
    if (tid < 512) xk[96 + tid] = (_Float16)tanhf_(gl[tid] + gl[512 + tid]);
    __syncthreads();
    // Q = O @ W_out^T  (K=512 split in 2)
    {
      const int v = tid & 511, kh2 = tid >> 9;
      const half8* w = (const half8*)(WoutF + (size_t)v * 512 + kh2 * 256);
      const half8* op = (const half8*)(xk + 96 + kh2 * 256);
      float acc = 0.f;
      for (int i = 0; i < 32; ++i) acc = dot8(w[i], op[i], acc);
      gl[kh2 * 512 + v] = acc;
    }
    __syncthreads();
    if (tid < 500) out[((size_t)b * 150 + t) * 500 + tid] = gl[tid] + gl[512 + tid];
    // next-iteration emb sync separates gl reads from next gates writes
  }
}

// ---------------- launcher ----------------

extern "C" void kernel_launch(void* const* d_in, const int* in_sizes, int n_in,
                              void* d_out, int out_size, void* d_ws, size_t ws_size,
                              hipStream_t stream) {
  (void)in_sizes; (void)n_in; (void)out_size; (void)ws_size;
  const float* Xb = (const float*)d_in[0];
  const int* lab = (const int*)d_in[1];
  const float* w1 = (const float*)d_in[2]; const float* b1 = (const float*)d_in[3];
  const float* w2 = (const float*)d_in[4]; const float* b2 = (const float*)d_in[5];
  const float* w3 = (const float*)d_in[6]; const float* b3 = (const float*)d_in[7];
  const float* w4 = (const float*)d_in[8]; const float* b4 = (const float*)d_in[9];
  const float* E = (const float*)d_in[10];
  const float* Wx = (const float*)d_in[11]; const float* Wh = (const float*)d_in[12];
  const float* blstm = (const float*)d_in[13];
  const float* Wv = (const float*)d_in[14]; const float* Wha = (const float*)d_in[15];
  const float* bat = (const float*)d_in[16]; const float* beta = (const float*)d_in[17];
  const float* WO = (const float*)d_in[18]; const float* Wout = (const float*)d_in[19];
  float* out = (float*)d_out;
  char* ws = (char*)d_ws;

  // workspace layout (bytes). RegA/RegB reused across CNN stages; e2v/VF overlay RegB
  constexpr size_t oRegA  = 0;                         // in1p | in3p
  constexpr size_t sRegA  = 38338560ULL;
  constexpr size_t oRegB  = 38338560ULL;               // pre2 | pre4 | e2v+VF
  constexpr size_t oE2V   = oRegB;                     // 32 MB f32
  constexpr size_t oVF    = oRegB + 33554432ULL;       // 16 MB f16
  constexpr size_t oIn2p  = 105447424ULL;              // 19,169,280
  constexpr size_t oV     = 124616704ULL;              // 16,777,216 (Vbuf bf16)
  constexpr size_t oAp2   = 141393920ULL;
  constexpr size_t oAp3   = 141541376ULL;
  constexpr size_t oAp4   = 142131200ULL;
  constexpr size_t oWvT   = 144490496ULL;
  constexpr size_t oWgF   = 145014784ULL;              // 4,587,520
  constexpr size_t oWhaF  = 149602304ULL;              // 524,288
  constexpr size_t oWOF   = 150126592ULL;              // 1,048,576
  constexpr size_t oWoutF = 151175168ULL;              // 524,288
  constexpr size_t oEf    = 151699456ULL;              // 80,000  (end ~151.8 MB)

  bf16* in1p = (bf16*)(ws + oRegA);
  bf16* in3p = (bf16*)(ws + oRegA);
  bf16* pre2 = (bf16*)(ws + oRegB);
  bf16* pre4 = (bf16*)(ws + oRegB);
  float* e2v = (float*)(ws + oE2V);
  _Float16* VF = (_Float16*)(ws + oVF);
  bf16* in2p = (bf16*)(ws + oIn2p);
  bf16* Vbuf = (bf16*)(ws + oV);
  bf16* Ap2 = (bf16*)(ws + oAp2);
  bf16* Ap3 = (bf16*)(ws + oAp3);
  bf16* Ap4 = (bf16*)(ws + oAp4);
  bf16* WvT = (bf16*)(ws + oWvT);
  _Float16* WgF = (_Float16*)(ws + oWgF);
  _Float16* WhaF = (_Float16*)(ws + oWhaF);
  _Float16* WOF = (_Float16*)(ws + oWOF);
  _Float16* WoutF = (_Float16*)(ws + oWoutF);
  _Float16* Ef = (_Float16*)(ws + oEf);

  // ---- prep ----
  k_pack_apack<<<(9 * 128 * 64 + 255) / 256, 256, 0, stream>>>(w2, Ap2, 128, 64);
  k_pack_apack<<<(9 * 256 * 128 + 255) / 256, 256, 0, stream>>>(w3, Ap3, 256, 128);
  k_pack_apack<<<(9 * 512 * 256 + 255) / 256, 256, 0, stream>>>(w4, Ap4, 512, 256);
  k_castT512<<<1024, 256, 0, stream>>>(Wv, WvT);
  k_wgf<<<8960, 256, 0, stream>>>(Wx, Wh, WgF);
  k_whaf<<<1024, 256, 0, stream>>>(Wha, WhaF);
  k_castf16<<<2048, 256, 0, stream>>>(WO, WOF, 524288);
  k_woutf<<<1024, 256, 0, stream>>>(Wout, WoutF);
  k_castf16<<<157, 256, 0, stream>>>(E, Ef, 40000);

  // ---- CNN ----
  hipMemsetAsync(ws + oRegA, 0, sRegA, stream);
  hipMemsetAsync(ws + oIn2p, 0, 19169280ULL, stream);
  k_conv1<<<dim3(64, 32, 32), 256, 0, stream>>>(Xb, w1, b1, in1p);
  k_convgemm<64, 128, 32, 256, 0><<<dim3(2048, 1), 256, 0, stream>>>(in1p, Ap2, b2, pre2);
  k_pool<<<4096, 256, 0, stream>>>(pre2, in2p, 32, 256, 128, 18, 130, 1);
  hipMemsetAsync(ws + oRegA, 0, sRegA, stream);
  k_convgemm<128, 256, 16, 128, 1><<<dim3(512, 2), 256, 0, stream>>>(in2p, Ap3, b3, in3p);
  k_convgemm<256, 512, 16, 128, 0><<<dim3(512, 4), 256, 0, stream>>>(in3p, Ap4, b4, pre4);
  k_pool<<<4096, 256, 0, stream>>>(pre4, Vbuf, 16, 128, 512, 8, 64, 0);  // -> V (b,l,c)
  k_vtrans<<<dim3(8, 8, 32), 256, 0, stream>>>(Vbuf, VF);                 // V (b,c,l) f16
  k_gemm_vproj<<<dim3(4, 128), 256, 0, stream>>>(Vbuf, WvT, bat, e2v);    // exp(2*Vproj)

  // ---- decoder: 32 independent blocks, no global sync ----
  k_dec<<<32, 1024, 0, stream>>>(WgF, WhaF, WOF, WoutF, e2v, VF, Ef, lab, blstm, beta, out);
}

// Round 5
// 16009.721 us; speedup vs baseline: 3.0001x; 3.0001x over previous
//
#include <hip/hip_runtime.h>
#include <hip/hip_bf16.h>
#include <stdint.h>

typedef __attribute__((ext_vector_type(8))) short short8;
typedef __attribute__((ext_vector_type(4))) short short4v;
typedef __attribute__((ext_vector_type(4))) float f32x4;
typedef _Float16 half2v __attribute__((ext_vector_type(2)));
typedef _Float16 half8 __attribute__((ext_vector_type(8)));
using bf16 = __hip_bfloat16;

__device__ __forceinline__ float bfb2f(unsigned short u) {
  union { unsigned u; float f; } x; x.u = ((unsigned)u) << 16; return x.f;
}
__device__ __forceinline__ unsigned short f2bfb(float f) {
  union { float f; unsigned u; } x; x.f = f;
  unsigned r = x.u + 0x7FFFu + ((x.u >> 16) & 1u);
  return (unsigned short)(r >> 16);
}
__device__ __forceinline__ float sigf(float x) { return 1.0f / (1.0f + __expf(-x)); }
__device__ __forceinline__ float tanhf_(float x) {
  x = fminf(fmaxf(x, -15.f), 15.f);
  float e = __expf(2.f * x);
  return 1.f - 2.f / (e + 1.f);
}
__device__ __forceinline__ f32x4 mfma16(short8 a, short8 b, f32x4 c) {
  return __builtin_amdgcn_mfma_f32_16x16x32_bf16(a, b, c, 0, 0, 0);
}
__device__ __forceinline__ int swz(int b) { return b ^ (((b >> 6) & 7) << 4); }

// f16 dot-8 with fp32 accumulate
__device__ __forceinline__ float dot8(half8 w, half8 x, float acc) {
#if __has_builtin(__builtin_amdgcn_fdot2)
  half2v w0 = {w[0], w[1]}, w1 = {w[2], w[3]}, w2 = {w[4], w[5]}, w3 = {w[6], w[7]};
  half2v x0 = {x[0], x[1]}, x1 = {x[2], x[3]}, x2 = {x[4], x[5]}, x3 = {x[6], x[7]};
  acc = __builtin_amdgcn_fdot2(w0, x0, acc, false);
  acc = __builtin_amdgcn_fdot2(w1, x1, acc, false);
  acc = __builtin_amdgcn_fdot2(w2, x2, acc, false);
  acc = __builtin_amdgcn_fdot2(w3, x3, acc, false);
#else
#pragma unroll
  for (int i = 0; i < 8; ++i) acc += (float)w[i] * (float)x[i];
#endif
  return acc;
}

// ---------------- prep / packing kernels ----------------

__global__ void k_pack_apack(const float* __restrict__ w, bf16* __restrict__ out, int CO, int CI) {
  int idx = blockIdx.x * 256 + threadIdx.x;
  int total = 9 * CO * CI;
  if (idx >= total) return;
  int ci = idx % CI; int r = idx / CI; int co = r % CO; int s = r / CO;
  ((unsigned short*)out)[(s * CO + co) * CI + ci] = f2bfb(w[(co * CI + ci) * 9 + s]);
}

__global__ void k_cast(const float* __restrict__ src, bf16* __restrict__ dst, int n) {
  int idx = blockIdx.x * 256 + threadIdx.x;
  if (idx < n) ((unsigned short*)dst)[idx] = f2bfb(src[idx]);
}

__global__ void k_castT512(const float* __restrict__ src, bf16* __restrict__ dst) {
  int idx = blockIdx.x * 256 + threadIdx.x;
  if (idx >= 262144) return;
  int k = idx >> 9, nn = idx & 511;
  ((unsigned short*)dst)[nn * 512 + k] = f2bfb(src[idx]);
}

__global__ void k_castf16(const float* __restrict__ src, _Float16* __restrict__ dst, int n) {
  int idx = blockIdx.x * 256 + threadIdx.x;
  if (idx < n) dst[idx] = (_Float16)src[idx];
}

// Gates B: bf16 MFMA-fragment-packed, K=1120 rows = [Wx[:,:80]|16 zero|Wx[:,80:592]|Wh], N=2048
__global__ void k_pack_wg(const float* __restrict__ Wx, const float* __restrict__ Wh, bf16* __restrict__ out) {
  int idx = blockIdx.x * 256 + threadIdx.x;
  if (idx >= 2293760) return;
  int kj = idx & 7, jc = (idx >> 3) & 15; int r = idx >> 7;
  int kg = r % 140, jblk = r / 140;
  int k = kg * 8 + kj, j = jblk * 16 + jc;
  float v = 0.f;
  if (k < 80) v = Wx[j * 592 + k];
  else if (k < 96) v = 0.f;
  else if (k < 608) v = Wx[j * 592 + k - 16];
  else v = Wh[j * 512 + k - 608];
  ((unsigned short*)out)[idx] = f2bfb(v);
}
// Wh_att transposed f16: WhaF[n][k] = Wha[k][n]
__global__ void k_whaf(const float* __restrict__ Wha, _Float16* __restrict__ out) {
  int idx = blockIdx.x * 256 + threadIdx.x;
  if (idx >= 262144) return;
  int k = idx & 511, n = idx >> 9;
  out[idx] = (_Float16)Wha[k * 512 + n];
}
// W_out f16 [512][512], rows >=500 zero
__global__ void k_woutf(const float* __restrict__ W, _Float16* __restrict__ out) {
  int idx = blockIdx.x * 256 + threadIdx.x;
  if (idx >= 262144) return;
  int v = idx >> 9;
  out[idx] = (v < 500) ? (_Float16)W[idx] : (_Float16)0.f;
}

// X rows(608): [emb80|pad16|O512]; Hb[2][32][512] zero; Cst zero
__global__ void k_init(bf16* __restrict__ X, bf16* __restrict__ Hb, float* __restrict__ Cst,
                       const bf16* __restrict__ Ebf) {
  int idx = blockIdx.x * 256 + threadIdx.x;
  if (idx < 32 * 608) {
    int k = idx % 608;
    unsigned short v = 0;
    if (k < 80) v = ((const unsigned short*)Ebf)[497 * 80 + k];  // start token = vocab-3
    ((unsigned short*)X)[idx] = v;
  }
  if (idx < 32768) ((unsigned short*)Hb)[idx] = 0;
  if (idx < 16384) Cst[idx] = 0.f;
}

// ---------------- CNN ----------------

__global__ __launch_bounds__(256) void k_conv1(const float* __restrict__ Xin, const float* __restrict__ w1,
                                               const float* __restrict__ b1, bf16* __restrict__ out) {
  __shared__ float wsm[576];
  __shared__ float xt[4][10];
  const int tid = threadIdx.x;
  const int n = blockIdx.z, y2 = blockIdx.y, xb = blockIdx.x * 4;
  for (int i = tid; i < 576; i += 256) wsm[i] = w1[i];
  if (tid < 40) {
    int rr = tid / 10, cc = tid % 10;
    int gy = 2 * y2 - 1 + rr, gx = 2 * xb - 1 + cc;
    float v = 0.f;
    if (gy >= 0 && gy < 64 && gx >= 0 && gx < 512) v = Xin[n * 32768 + gy * 512 + gx];
    xt[rr][cc] = v;
  }
  __syncthreads();
  const int co = tid & 63, xl = tid >> 6;
  const float bb = b1[co];
  float mx = 0.f;
#pragma unroll
  for (int py = 0; py < 2; ++py)
#pragma unroll
    for (int px = 0; px < 2; ++px) {
      float s = bb;
#pragma unroll
      for (int dy = 0; dy < 3; ++dy)
#pragma unroll
        for (int dx = 0; dx < 3; ++dx)
          s = fmaf(wsm[co * 9 + dy * 3 + dx], xt[py + dy][2 * xl + px + dx], s);
      mx = fmaxf(mx, fmaxf(s, 0.f));
    }
  ((unsigned short*)out)[((n * 34 + y2 + 1) * 258 + (xb + xl) + 1) * 64 + co] = f2bfb(mx);
}

template <int CI, int CO, int H, int W, int MODE>
__global__ __launch_bounds__(256) void k_convgemm(const bf16* __restrict__ inP, const bf16* __restrict__ apack,
                                                  const float* __restrict__ bias, bf16* __restrict__ outp) {
  constexpr int Hp = H + 2, Wp = W + 2;
  __shared__ __align__(16) char As[8192];
  __shared__ __align__(16) char Bs[8192];
  const int tid = threadIdx.x, lane = tid & 63, wv = tid >> 6;
  const int lm = lane & 15, kh = lane >> 4;
  const int wm = wv & 1, wn = wv >> 1;
  const int p0 = blockIdx.x * 128, m0 = blockIdx.y * 128;
  const int n = p0 / (H * W), rem = p0 % (H * W);
  const int y = rem / W, x0 = rem % W;
  const long long pixbase = ((long long)(n * Hp + y) * Wp + x0) * CI;
  f32x4 acc[4][4];
#pragma unroll
  for (int i = 0; i < 4; ++i)
#pragma unroll
    for (int j = 0; j < 4; ++j) acc[i][j] = (f32x4){0.f, 0.f, 0.f, 0.f};
  const int r = tid >> 1, e0 = (tid & 1) * 16;
  const int wb = r * 64 + e0 * 2;
  for (int s = 0; s < 9; ++s) {
    const int dy = s / 3, dx = s % 3;
    const bf16* bsrc = inP + pixbase + (dy * Wp + dx) * CI;
    const bf16* asrc = apack + (s * CO + m0) * CI;
    for (int cc = 0; cc < CI / 32; ++cc) {
      short8 av0 = *(const short8*)(asrc + r * CI + cc * 32 + e0);
      short8 av1 = *(const short8*)(asrc + r * CI + cc * 32 + e0 + 8);
      short8 bv0 = *(const short8*)(bsrc + (long long)r * CI + cc * 32 + e0);
      short8 bv1 = *(const short8*)(bsrc + (long long)r * CI + cc * 32 + e0 + 8);
      __syncthreads();
      *(short8*)(void*)(As + swz(wb)) = av0;
      *(short8*)(void*)(As + swz(wb + 16)) = av1;
      *(short8*)(void*)(Bs + swz(wb)) = bv0;
      *(short8*)(void*)(Bs + swz(wb + 16)) = bv1;
      __syncthreads();
      short8 af[4], bg[4];
#pragma unroll
      for (int i = 0; i < 4; ++i)
        af[i] = *(const short8*)(const void*)(As + swz((wm * 64 + i * 16 + lm) * 64 + kh * 16));
#pragma unroll
      for (int j = 0; j < 4; ++j)
        bg[j] = *(const short8*)(const void*)(Bs + swz((wn * 64 + j * 16 + lm) * 64 + kh * 16));
#pragma unroll
      for (int i = 0; i < 4; ++i)
#pragma unroll
        for (int j = 0; j < 4; ++j) acc[i][j] = mfma16(af[i], bg[j], acc[i][j]);
    }
  }
#pragma unroll
  for (int i = 0; i < 4; ++i) {
    const int co = m0 + wm * 64 + i * 16 + kh * 4;
    float b4[4];
#pragma unroll
    for (int rr = 0; rr < 4; ++rr) b4[rr] = bias[co + rr];
#pragma unroll
    for (int j = 0; j < 4; ++j) {
      const int pix = p0 + wn * 64 + j * 16 + lm;
      short4v pk;
#pragma unroll
      for (int rr = 0; rr < 4; ++rr) {
        float v = fmaxf(acc[i][j][rr] + b4[rr], 0.f);
        pk[rr] = (short)f2bfb(v);
      }
      if constexpr (MODE == 0) {
        *(short4v*)(void*)(outp + (long long)pix * CO + co) = pk;
      } else {
        const int nn = pix / (H * W), r2 = pix % (H * W);
        const int yy = r2 / W, xx = r2 % W;
        *(short4v*)(void*)(outp + ((long long)(nn * Hp + yy + 1) * Wp + xx + 1) * CO + co) = pk;
      }
    }
  }
}

__global__ void k_pool(const bf16* __restrict__ src, bf16* __restrict__ dst,
                       int H, int W, int C, int OHP, int OWP, int pad) {
  const int idx = blockIdx.x * 256 + threadIdx.x;
  const int C8 = C >> 3;
  const int c8 = idx % C8; int tmp = idx / C8;
  const int x2 = tmp % (W >> 1); tmp /= (W >> 1);
  const int y2 = tmp % (H >> 1); const int n = tmp / (H >> 1);
  if (n >= 32) return;
  const long long sbase = ((long long)(n * H + 2 * y2) * W + 2 * x2) * C + c8 * 8;
  short8 a = *(const short8*)(src + sbase);
  short8 b = *(const short8*)(src + sbase + C);
  short8 c = *(const short8*)(src + sbase + (long long)W * C);
  short8 d = *(const short8*)(src + sbase + (long long)W * C + C);
  short8 o;
#pragma unroll
  for (int e = 0; e < 8; ++e) {
    float m = fmaxf(fmaxf(bfb2f((unsigned short)a[e]), bfb2f((unsigned short)b[e])),
                    fmaxf(bfb2f((unsigned short)c[e]), bfb2f((unsigned short)d[e])));
    o[e] = (short)f2bfb(m);
  }
  *(short8*)(void*)(dst + ((long long)(n * OHP + y2 + pad) * OWP + x2 + pad) * C + c8 * 8) = o;
}

// tiled transpose: VF[(b*512+c)*512+l] = f16(Vbuf[(b*512+l)*512+c])
__global__ __launch_bounds__(256) void k_vtrans(const bf16* __restrict__ V, _Float16* __restrict__ VF) {
  __shared__ _Float16 tile[64][65];
  const int b = blockIdx.z, lt = blockIdx.y * 64, ct = blockIdx.x * 64;
  const int tid = threadIdx.x;
  const int row = tid >> 2, cg = (tid & 3) * 16;
  const unsigned short* src = (const unsigned short*)V + ((size_t)(b * 512 + lt + row) * 512) + ct + cg;
#pragma unroll
  for (int i = 0; i < 16; ++i) tile[row][cg + i] = (_Float16)bfb2f(src[i]);
  __syncthreads();
  const int crow = tid >> 2, lg = (tid & 3) * 16;
  _Float16* dst = VF + ((size_t)(b * 512 + ct + crow) * 512) + lt + lg;
#pragma unroll
  for (int i = 0; i < 16; ++i) dst[i] = tile[lg + i][crow];
}

// Vproj GEMM -> e2v = exp(2*(V@Wv + b_att)) f32
__global__ __launch_bounds__(256) void k_gemm_vproj(const bf16* __restrict__ Vb, const bf16* __restrict__ WvT,
                                                    const float* __restrict__ batt, float* __restrict__ E2V) {
  __shared__ __align__(16) char As[8192];
  __shared__ __align__(16) char Bs[8192];
  const int tid = threadIdx.x, lane = tid & 63, wv = tid >> 6;
  const int lm = lane & 15, kh = lane >> 4;
  const int wm = wv & 1, wn = wv >> 1;
  const int n0 = blockIdx.x * 128, m0 = blockIdx.y * 128;
  f32x4 acc[4][4];
#pragma unroll
  for (int i = 0; i < 4; ++i)
#pragma unroll
    for (int j = 0; j < 4; ++j) acc[i][j] = (f32x4){0.f, 0.f, 0.f, 0.f};
  const int r = tid >> 1, e0 = (tid & 1) * 16;
  const int wb = r * 64 + e0 * 2;
  for (int cc = 0; cc < 16; ++cc) {
    short8 av0 = *(const short8*)(Vb + (m0 + r) * 512 + cc * 32 + e0);
    short8 av1 = *(const short8*)(Vb + (m0 + r) * 512 + cc * 32 + e0 + 8);
    short8 bv0 = *(const short8*)(WvT + (n0 + r) * 512 + cc * 32 + e0);
    short8 bv1 = *(const short8*)(WvT + (n0 + r) * 512 + cc * 32 + e0 + 8);
    __syncthreads();
    *(short8*)(void*)(As + swz(wb)) = av0;
    *(short8*)(void*)(As + swz(wb + 16)) = av1;
    *(short8*)(void*)(Bs + swz(wb)) = bv0;
    *(short8*)(void*)(Bs + swz(wb + 16)) = bv1;
    __syncthreads();
    short8 af[4], bg[4];
#pragma unroll
    for (int i = 0; i < 4; ++i)
      af[i] = *(const short8*)(const void*)(As + swz((wm * 64 + i * 16 + lm) * 64 + kh * 16));
#pragma unroll
    for (int j = 0; j < 4; ++j)
      bg[j] = *(const short8*)(const void*)(Bs + swz((wn * 64 + j * 16 + lm) * 64 + kh * 16));
#pragma unroll
    for (int i = 0; i < 4; ++i)
#pragma unroll
      for (int j = 0; j < 4; ++j) acc[i][j] = mfma16(af[i], bg[j], acc[i][j]);
  }
#pragma unroll
  for (int i = 0; i < 4; ++i)
#pragma unroll
    for (int j = 0; j < 4; ++j) {
      const int nn = n0 + wn * 64 + j * 16 + lm;
      const float ba = batt[nn];
#pragma unroll
      for (int rr = 0; rr < 4; ++rr) {
        const int m = m0 + wm * 64 + i * 16 + kh * 4 + rr;
        E2V[(size_t)m * 512 + nn] = __expf(2.f * (acc[i][j][rr] + ba));
      }
    }
}

// ---------------- decoder step kernel 1: batched gates MFMA + LSTM ----------------
// 32 blocks x 256 thr; block nb owns hid slice [nb*16, nb*16+16). Cell state in global f32.
__global__ __launch_bounds__(256) void k_gates(int t, const bf16* __restrict__ X,
                                               bf16* __restrict__ Hb, _Float16* __restrict__ Hf,
                                               float* __restrict__ Cst, const bf16* __restrict__ WgP,
                                               const float* __restrict__ bl) {
  const int tid = threadIdx.x, lane = tid & 63, wv = tid >> 6;
  const int lm = lane & 15, kh = lane >> 4;
  const int nb = blockIdx.x;
  const int jblk = wv * 32 + nb;
  const bf16* hprev = Hb + ((t + 1) & 1) * 16384;
  f32x4 acc0 = {0.f, 0.f, 0.f, 0.f}, acc1 = {0.f, 0.f, 0.f, 0.f};
  for (int kk = 0; kk < 19; ++kk) {
    short8 a0 = *(const short8*)(X + lm * 608 + kk * 32 + kh * 8);
    short8 a1 = *(const short8*)(X + (lm + 16) * 608 + kk * 32 + kh * 8);
    short8 bw = *(const short8*)(WgP + ((jblk * 140 + kk * 4 + kh) * 16 + lm) * 8);
    acc0 = mfma16(a0, bw, acc0); acc1 = mfma16(a1, bw, acc1);
  }
  for (int kk = 19; kk < 35; ++kk) {
    short8 a0 = *(const short8*)(hprev + lm * 512 + (kk - 19) * 32 + kh * 8);
    short8 a1 = *(const short8*)(hprev + (lm + 16) * 512 + (kk - 19) * 32 + kh * 8);
    short8 bw = *(const short8*)(WgP + ((jblk * 140 + kk * 4 + kh) * 16 + lm) * 8);
    acc0 = mfma16(a0, bw, acc0); acc1 = mfma16(a1, bw, acc1);
  }
  __shared__ float gl[4][32][16];
  const float bj = bl[wv * 512 + nb * 16 + lm];
#pragma unroll
  for (int rr = 0; rr < 4; ++rr) {
    gl[wv][kh * 4 + rr][lm] = acc0[rr] + bj;
    gl[wv][16 + kh * 4 + rr][lm] = acc1[rr] + bj;
  }
  __syncthreads();
  unsigned short* hcur = (unsigned short*)(Hb + (t & 1) * 16384);
  for (int idx = tid; idx < 512; idx += 256) {
    const int b = idx >> 4, hh = idx & 15;
    const int hid = nb * 16 + hh;
    float ig = gl[0][b][hh], fg = gl[1][b][hh], gg = gl[2][b][hh], og = gl[3][b][hh];
    float c = sigf(fg) * Cst[b * 512 + hid] + sigf(ig) * tanhf_(gg);
    Cst[b * 512 + hid] = c;
    float hf32 = sigf(og) * tanhf_(c);
    hcur[b * 512 + hid] = f2bfb(hf32);
    Hf[b * 512 + hid] = (_Float16)hf32;
  }
}

// ---------------- decoder step kernel 2: per-b attention + O + Q + X update ----------------
// 32 blocks (block=b) x 1024 thr (16 waves). All phases: wave-per-output, lane-per-K,
// coalesced 16B/lane global loads, shfl-reduce. tanh(v+h) = 1 - 2/(1+e2v*e2h).
__global__ __launch_bounds__(1024) void k_att(int t,
    const _Float16* __restrict__ Hf, bf16* __restrict__ X,
    const _Float16* __restrict__ WhaF, const float* __restrict__ e2v,
    const _Float16* __restrict__ VF, const _Float16* __restrict__ WOF,
    const _Float16* __restrict__ WoutF, const bf16* __restrict__ Ebf,
    const int* __restrict__ labels, const float* __restrict__ beta,
    float* __restrict__ out) {
  const int tid = threadIdx.x, b = blockIdx.x;
  const int lane = tid & 63, wv = tid >> 6;
  __shared__ _Float16 hcs[1024];  // [h | ctx] f16
  __shared__ float hb2[1024];     // interleaved (e^{2hW[n]}, beta[n])
  __shared__ float sb[512];       // scores -> softmax weights
  __shared__ float red[16];
  __shared__ _Float16 Of[512];
  if (tid < 512) hcs[tid] = Hf[b * 512 + tid];
  __syncthreads();
  // hW[n] = h . WhaF[n][:], then e^{2hW}
  {
    half8 x8 = *(const half8*)(hcs + lane * 8);
    for (int i = 0; i < 32; ++i) {
      const int n = wv * 32 + i;
      half8 w8 = *(const half8*)(WhaF + (size_t)n * 512 + lane * 8);
      float p = dot8(w8, x8, 0.f);
#pragma unroll
      for (int off = 32; off >= 1; off >>= 1) p += __shfl_xor(p, off, 64);
      if (lane == 0) { hb2[2 * n] = __expf(2.f * p); hb2[2 * n + 1] = beta[n]; }
    }
  }
  __syncthreads();
  // scores[l] = sum_n beta_n * (1 - 2/(1 + e2v[l][n]*e2h[n]))
  {
    const f32x4* hp = (const f32x4*)hb2 + lane * 4;
    f32x4 h0 = hp[0], h1 = hp[1], h2 = hp[2], h3 = hp[3];
    for (int i = 0; i < 32; ++i) {
      const int l = wv * 32 + i;
      const f32x4* ep = (const f32x4*)(e2v + ((size_t)(b * 512 + l)) * 512 + lane * 8);
      f32x4 e0 = ep[0], e1 = ep[1];
      float r, acc;
      r = __builtin_amdgcn_rcpf(1.f + e0[0] * h0[0]); acc = h0[1] * fmaf(-2.f, r, 1.f);
      r = __builtin_amdgcn_rcpf(1.f + e0[1] * h0[2]); acc = fmaf(h0[3], fmaf(-2.f, r, 1.f), acc);
      r = __builtin_amdgcn_rcpf(1.f + e0[2] * h1[0]); acc = fmaf(h1[1], fmaf(-2.f, r, 1.f), acc);
      r = __builtin_amdgcn_rcpf(1.f + e0[3] * h1[2]); acc = fmaf(h1[3], fmaf(-2.f, r, 1.f), acc);
      r = __builtin_amdgcn_rcpf(1.f + e1[0] * h2[0]); acc = fmaf(h2[1], fmaf(-2.f, r, 1.f), acc);
      r = __builtin_amdgcn_rcpf(1.f + e1[1] * h2[2]); acc = fmaf(h2[3], fmaf(-2.f, r, 1.f), acc);
      r = __builtin_amdgcn_rcpf(1.f + e1[2] * h3[0]); acc = fmaf(h3[1], fmaf(-2.f, r, 1.f), acc);
      r = __builtin_amdgcn_rcpf(1.f + e1[3] * h3[2]); acc = fmaf(h3[3], fmaf(-2.f, r, 1.f), acc);
#pragma unroll
      for (int off = 32; off >= 1; off >>= 1) acc += __shfl_xor(acc, off, 64);
      if (lane == 0) sb[l] = acc;
    }
  }
  __syncthreads();
  // softmax over 512 (threads 0..511)
  if (tid < 512) {
    float s = sb[tid];
    float m = s;
#pragma unroll
    for (int off = 32; off >= 1; off >>= 1) m = fmaxf(m, __shfl_xor(m, off, 64));
    if (lane == 0) red[tid >> 6] = m;
  }
  __syncthreads();
  if (tid < 512) {
    float m = fmaxf(fmaxf(fmaxf(red[0], red[1]), fmaxf(red[2], red[3])),
                    fmaxf(fmaxf(red[4], red[5]), fmaxf(red[6], red[7])));
    float e = __expf(sb[tid] - m);
    sb[tid] = e;
    float sm = e;
#pragma unroll
    for (int off = 32; off >= 1; off >>= 1) sm += __shfl_xor(sm, off, 64);
    if (lane == 0) red[8 + (tid >> 6)] = sm;
  }
  __syncthreads();
  // ctx[c] = (1/Z) sum_l a_l * V[b][c][l]
  {
    float Z = 0.f;
#pragma unroll
    for (int i = 0; i < 8; ++i) Z += red[8 + i];
    const float rz = 1.f / Z;
    const f32x4* ap = (const f32x4*)sb + lane * 2;
    f32x4 a0 = ap[0], a1 = ap[1];
    for (int i = 0; i < 32; ++i) {
      const int c = wv * 32 + i;
      half8 v8 = *(const half8*)(VF + ((size_t)(b * 512 + c)) * 512 + lane * 8);
      float acc = (float)v8[0] * a0[0];
      acc = fmaf((float)v8[1], a0[1], acc);
      acc = fmaf((float)v8[2], a0[2], acc);
      acc = fmaf((float)v8[3], a0[3], acc);
      acc = fmaf((float)v8[4], a1[0], acc);
      acc = fmaf((float)v8[5], a1[1], acc);
      acc = fmaf((float)v8[6], a1[2], acc);
      acc = fmaf((float)v8[7], a1[3], acc);
#pragma unroll
      for (int off = 32; off >= 1; off >>= 1) acc += __shfl_xor(acc, off, 64);
      if (lane == 0) hcs[512 + c] = (_Float16)(acc * rz);
    }
  }
  __syncthreads();
  // O[o] = tanh([h|ctx] . WOF[o][:])
  {
    half8 xa = *(const half8*)(hcs + lane * 8);
    half8 xb = *(const half8*)(hcs + 512 + lane * 8);
    unsigned short* Xu = (unsigned short*)X;
    for (int i = 0; i < 32; ++i) {
      const int o = wv * 32 + i;
      half8 w0 = *(const half8*)(WOF + (size_t)o * 1024 + lane * 8);
      half8 w1 = *(const half8*)(WOF + (size_t)o * 1024 + 512 + lane * 8);
      float p = dot8(w1, xb, dot8(w0, xa, 0.f));
#pragma unroll
      for (int off = 32; off >= 1; off >>= 1) p += __shfl_xor(p, off, 64);
      if (lane == 0) {
        float ov = tanhf_(p);
        Of[o] = (_Float16)ov;
        Xu[b * 608 + 96 + o] = f2bfb(ov);
      }
    }
  }
  __syncthreads();
  // Q[v] = O . WoutF[v][:]
  {
    half8 oa = *(const half8*)(Of + lane * 8);
    for (int i = 0; i < 32; ++i) {
      const int v = wv * 32 + i;
      half8 w8 = *(const half8*)(WoutF + (size_t)v * 512 + lane * 8);
      float p = dot8(w8, oa, 0.f);
#pragma unroll
      for (int off = 32; off >= 1; off >>= 1) p += __shfl_xor(p, off, 64);
      if (lane == 0 && v < 500) out[((size_t)b * 150 + t) * 500 + v] = p;
    }
  }
  // stage emb(t+1)
  if (t + 1 < 150 && tid < 80) {
    const int id = labels[b * 150 + t];
    ((unsigned short*)X)[b * 608 + tid] = ((const unsigned short*)Ebf)[id * 80 + tid];
  }
}

// ---------------- launcher ----------------

extern "C" void kernel_launch(void* const* d_in, const int* in_sizes, int n_in,
                              void* d_out, int out_size, void* d_ws, size_t ws_size,
                              hipStream_t stream) {
  (void)in_sizes; (void)n_in; (void)out_size; (void)ws_size;
  const float* Xb = (const float*)d_in[0];
  const int* lab = (const int*)d_in[1];
  const float* w1 = (const float*)d_in[2]; const float* b1 = (const float*)d_in[3];
  const float* w2 = (const float*)d_in[4]; const float* b2 = (const float*)d_in[5];
  const float* w3 = (const float*)d_in[6]; const float* b3 = (const float*)d_in[7];
  const float* w4 = (const float*)d_in[8]; const float* b4 = (const float*)d_in[9];
  const float* E = (const float*)d_in[10];
  const float* Wx = (const float*)d_in[11]; const float* Wh = (const float*)d_in[12];
  const float* blstm = (const float*)d_in[13];
  const float* Wv = (const float*)d_in[14]; const float* Wha = (const float*)d_in[15];
  const float* bat = (const float*)d_in[16]; const float* beta = (const float*)d_in[17];
  const float* WO = (const float*)d_in[18]; const float* Wout = (const float*)d_in[19];
  float* out = (float*)d_out;
  char* ws = (char*)d_ws;

  // workspace layout (bytes). RegA/RegB reused across CNN; e2v/VF overlay RegB.
  constexpr size_t oRegA  = 0;                       // in1p | in3p
  constexpr size_t sRegA  = 38338560ULL;
  constexpr size_t oRegB  = 38338560ULL;             // pre2 | pre4 | (e2v,VF)
  constexpr size_t oE2V   = oRegB;                   // 33,554,432 f32
  constexpr size_t oVF    = oRegB + 33554432ULL;     // 16,777,216 f16
  constexpr size_t oIn2p  = 105447424ULL;            // 19,169,280
  constexpr size_t oV     = 124616704ULL;            // 16,777,216
  constexpr size_t oAp2   = 141393920ULL;
  constexpr size_t oAp3   = 141541376ULL;
  constexpr size_t oAp4   = 142131200ULL;
  constexpr size_t oWvT   = 144490496ULL;
  constexpr size_t oWgP   = 145014784ULL;            // 4,587,520
  constexpr size_t oWhaF  = 149602304ULL;            // 524,288
  constexpr size_t oWOF   = 150126592ULL;            // 1,048,576
  constexpr size_t oWoutF = 151175168ULL;            // 524,288
  constexpr size_t oEbf   = 151699456ULL;            // 80,128
  constexpr size_t oX     = 151779584ULL;            // 39,168
  constexpr size_t oHb    = 151818752ULL;            // 65,536 (2 slots)
  constexpr size_t oHf    = 151884288ULL;            // 32,768
  constexpr size_t oCst   = 151917056ULL;            // 65,536  (end ~152 MB)

  bf16* in1p = (bf16*)(ws + oRegA);
  bf16* in3p = (bf16*)(ws + oRegA);
  bf16* pre2 = (bf16*)(ws + oRegB);
  bf16* pre4 = (bf16*)(ws + oRegB);
  float* e2v = (float*)(ws + oE2V);
  _Float16* VF = (_Float16*)(ws + oVF);
  bf16* in2p = (bf16*)(ws + oIn2p);
  bf16* Vbuf = (bf16*)(ws + oV);
  bf16* Ap2 = (bf16*)(ws + oAp2);
  bf16* Ap3 = (bf16*)(ws + oAp3);
  bf16* Ap4 = (bf16*)(ws + oAp4);
  bf16* WvT = (bf16*)(ws + oWvT);
  bf16* WgP = (bf16*)(ws + oWgP);
  _Float16* WhaF = (_Float16*)(ws + oWhaF);
  _Float16* WOF = (_Float16*)(ws + oWOF);
  _Float16* WoutF = (_Float16*)(ws + oWoutF);
  bf16* Ebf = (bf16*)(ws + oEbf);
  bf16* X = (bf16*)(ws + oX);
  bf16* Hb = (bf16*)(ws + oHb);
  _Float16* Hf = (_Float16*)(ws + oHf);
  float* Cst = (float*)(ws + oCst);

  // ---- prep ----
  k_pack_apack<<<(9 * 128 * 64 + 255) / 256, 256, 0, stream>>>(w2, Ap2, 128, 64);
  k_pack_apack<<<(9 * 256 * 128 + 255) / 256, 256, 0, stream>>>(w3, Ap3, 256, 128);
  k_pack_apack<<<(9 * 512 * 256 + 255) / 256, 256, 0, stream>>>(w4, Ap4, 512, 256);
  k_castT512<<<1024, 256, 0, stream>>>(Wv, WvT);
  k_pack_wg<<<8960, 256, 0, stream>>>(Wx, Wh, WgP);
  k_whaf<<<1024, 256, 0, stream>>>(Wha, WhaF);
  k_castf16<<<2048, 256, 0, stream>>>(WO, WOF, 524288);
  k_woutf<<<1024, 256, 0, stream>>>(Wout, WoutF);
  k_cast<<<(40000 + 255) / 256, 256, 0, stream>>>(E, Ebf, 40000);

  // ---- CNN ----
  hipMemsetAsync(ws + oRegA, 0, sRegA, stream);
  hipMemsetAsync(ws + oIn2p, 0, 19169280ULL, stream);
  k_conv1<<<dim3(64, 32, 32), 256, 0, stream>>>(Xb, w1, b1, in1p);
  k_convgemm<64, 128, 32, 256, 0><<<dim3(2048, 1), 256, 0, stream>>>(in1p, Ap2, b2, pre2);
  k_pool<<<4096, 256, 0, stream>>>(pre2, in2p, 32, 256, 128, 18, 130, 1);
  hipMemsetAsync(ws + oRegA, 0, sRegA, stream);
  k_convgemm<128, 256, 16, 128, 1><<<dim3(512, 2), 256, 0, stream>>>(in2p, Ap3, b3, in3p);
  k_convgemm<256, 512, 16, 128, 0><<<dim3(512, 4), 256, 0, stream>>>(in3p, Ap4, b4, pre4);
  k_pool<<<4096, 256, 0, stream>>>(pre4, Vbuf, 16, 128, 512, 8, 64, 0);   // -> V (b,l,c)
  k_vtrans<<<dim3(8, 8, 32), 256, 0, stream>>>(Vbuf, VF);                  // V (b,c,l) f16
  k_gemm_vproj<<<dim3(4, 128), 256, 0, stream>>>(Vbuf, WvT, bat, e2v);     // exp(2*Vproj)

  // ---- decoder: 2 kernels per step, sync via kernel boundaries ----
  k_init<<<128, 256, 0, stream>>>(X, Hb, Cst, Ebf);
  for (int t = 0; t < 150; ++t) {
    k_gates<<<32, 256, 0, stream>>>(t, X, Hb, Hf, Cst, WgP, blstm);
    k_att<<<32, 1024, 0, stream>>>(t, Hf, X, WhaF, e2v, VF, WOF, WoutF, Ebf, lab, beta, out);
  }
}